// Round 1
// baseline (173.755 us; speedup 1.0000x reference)
//
#include <hip/hip_runtime.h>
#include <hip/hip_bf16.h>
#include <stdint.h>

typedef unsigned short u16;
typedef __attribute__((ext_vector_type(8))) short short8;
typedef __attribute__((ext_vector_type(4))) float floatx4;

#define N_IMG 4
#define C_IN  2048
#define HW    1024
#define KK    9
#define O_OUT 256
#define NPIX  4096          // N_IMG*HW
#define M_PAD  2560         // 10*256 GEMM M-tiles (2304 proj + 81 conv + pad)
#define H_ROWS 2432         // H rows actually stored (proj 2304 + conv 81 + pad)
#define K_DIM  2048
#define BN_EPS 1e-5f

// workspace offsets (bytes), 256-aligned
#define OFF_A    0u                // A: 2560*2048*2 = 10485760
#define OFF_XT   10485760u         // XT: 4096*2048*2 = 16777216
#define OFF_H    27262976u         // H: 2432*4096*2 = 19922944
#define OFF_SRAW 47185920u         // sraw: 36864*4
#define OFF_STAT 47333376u

// fp32 -> bf16 bits, round-to-nearest-even
__device__ __forceinline__ u16 f2b(float f) {
    unsigned u = __float_as_uint(f);
    return (u16)((u + 0x7FFFu + ((u >> 16) & 1u)) >> 16);
}

__device__ __forceinline__ void load8f(const float* base, size_t eidx, u16* out) {
    const float* p = base + eidx;
    float4 a = ((const float4*)p)[0];
    float4 b = ((const float4*)p)[1];
    float f[8] = {a.x, a.y, a.z, a.w, b.x, b.y, b.z, b.w};
#pragma unroll
    for (int j = 0; j < 8; ++j) out[j] = f2b(f[j]);
}

// ---------------- merged staging kernel (R10-validated, unchanged) ----------------
__global__ void build_all(const float* __restrict__ x, const float* __restrict__ wgt,
                          const float* __restrict__ cw, u16* __restrict__ xt,
                          u16* __restrict__ A, float* __restrict__ stats) {
    __shared__ __align__(16) u16 lds[9 * 2056];
    int b = blockIdx.x, t = threadIdx.x;
    if (b < 2048) {
        int c0 = (b & 31) * 64, p0 = ((b >> 5) & 15) * 64, n = b >> 9;
        int rp = t >> 3;                // channel-pair 0..31
        int pv = (t & 7) * 8;           // pixel group
        u16 h0[8], h1[8];
        load8f(x, (size_t)(n * C_IN + c0 + 2 * rp) * HW + p0 + pv, h0);
        load8f(x, (size_t)(n * C_IN + c0 + 2 * rp + 1) * HW + p0 + pv, h1);
        unsigned* l32 = (unsigned*)lds;   // [64 pixels][stride 35 u32]
#pragma unroll
        for (int j = 0; j < 8; ++j)
            l32[(pv + j) * 35 + rp] = (unsigned)h0[j] | ((unsigned)h1[j] << 16);
        __syncthreads();
        int pr = t >> 3, cq = (t & 7) * 4;   // pixel, u32-quad (8 channels)
        unsigned o0[4], o1[4];
#pragma unroll
        for (int i = 0; i < 4; ++i) {
            o0[i] = l32[pr * 35 + cq + i];
            o1[i] = l32[(pr + 32) * 35 + cq + i];
        }
        *(uint4*)(xt + (size_t)(n * HW + p0 + pr) * K_DIM + c0 + cq * 2) = *(uint4*)o0;
        *(uint4*)(xt + (size_t)(n * HW + p0 + pr + 32) * K_DIM + c0 + cq * 2) = *(uint4*)o1;
    } else if (b < 2304) {
        int o = b - 2048;
        size_t base = (size_t)o * 18432;   // weight[o][c][l], e = c*9+l
        for (int i = 0; i < 9; ++i) {
            int e0 = (t + i * 256) * 8;
            u16 hv[8];
            load8f(wgt, base + e0, hv);
#pragma unroll
            for (int j = 0; j < 8; ++j) {
                int e = e0 + j;
                int c = e / 9, l = e - c * 9;
                lds[l * 2056 + c] = hv[j];
            }
        }
        __syncthreads();
        for (int l = 0; l < 9; ++l) {
            size_t row = (size_t)l * 256 + o;
            *(uint4*)(A + row * K_DIM + t * 8) = *(const uint4*)&lds[l * 2056 + t * 8];
        }
    } else if (b < 2313) {
        int l = b - 2304;
        size_t base = (size_t)l * 18432;    // conv_w[l][c][k], e = c*9+k
        for (int i = 0; i < 9; ++i) {
            int e0 = (t + i * 256) * 8;
            u16 hv[8];
            load8f(cw, base + e0, hv);
#pragma unroll
            for (int j = 0; j < 8; ++j) {
                int e = e0 + j;
                int c = e / 9, k = e - c * 9;
                lds[k * 2056 + c] = hv[j];
            }
        }
        __syncthreads();
        for (int k = 0; k < 9; ++k) {
            size_t row = 2304 + (size_t)k * 9 + l;
            *(uint4*)(A + row * K_DIM + t * 8) = *(const uint4*)&lds[k * 2056 + t * 8];
        }
    } else {
        // zero A rows 2385..2431 (rows 2432..2559 are garbage but each H row
        // depends only on its own A row; those H rows are never stored)
        uint4 z = {0, 0, 0, 0};
        uint4* dst = (uint4*)(A + (size_t)2385 * K_DIM);
        for (int i = t; i < (47 * 2048) / 8; i += 256) dst[i] = z;
        if (t < 18) stats[t] = 0.0f;
    }
}

// ---------------- GEMM: H = A * XT^T ----------------
// R11: 256x256 tile, BK=64, 8 waves (2Mx4N), 8-phase counted-vmcnt pipeline
// (T2 LDS XOR-swizzle + T3/T4 + T5 setprio + T1 XCD swizzle, per m201 template)
__device__ __forceinline__ void gload_lds16(const void* g, void* l) {
    __builtin_amdgcn_global_load_lds((__attribute__((address_space(1))) void*)(g),
                                     (__attribute__((address_space(3))) void*)(l), 16, 0, 0);
}

// stage one 128-row half-tile slice for this wave: 2 x global_load_lds (1 KB each)
// LDS dest is linear; global source column is pre-swizzled (rule #21):
// lane L covers row lr=L>>3 (within its 8-row slab), cols 8*((L&7)^lr)..+8
#define STG(gbase, ldsarr, bb, hh, kt) do {                                                        \
    gload_lds16((gbase) + (size_t)((hh) * 128 + (w * 2 + 0) * 8) * K_DIM + (size_t)(kt) * 64,      \
                (ldsarr) + (bb) * 16384 + (hh) * 8192 + ldsw);                                     \
    gload_lds16((gbase) + (size_t)((hh) * 128 + (w * 2 + 1) * 8) * K_DIM + (size_t)(kt) * 64,      \
                (ldsarr) + (bb) * 16384 + (hh) * 8192 + ldsw + 512);                               \
} while (0)

#define RD_A(bb, mi, ks) (*(const short8*)(As + (bb) * 16384 + arow + (mi) * 1024 + col[ks]))
#define RD_B(bb, ni, ks) (*(const short8*)(Bs + (bb) * 16384 + brow + (ni) * 1024 + col[ks]))

#define READ_BALL(bb) do {                                                   \
    bq[0][0] = RD_B(bb, 0, 0); bq[0][1] = RD_B(bb, 0, 1);                    \
    bq[1][0] = RD_B(bb, 1, 0); bq[1][1] = RD_B(bb, 1, 1);                    \
    bq[2][0] = RD_B(bb, 2, 0); bq[2][1] = RD_B(bb, 2, 1);                    \
    bq[3][0] = RD_B(bb, 3, 0); bq[3][1] = RD_B(bb, 3, 1);                    \
} while (0)

#define READ_AQ(bb, qd) do {                                                 \
    aq[0][0] = RD_A(bb, 2 * (qd), 0);     aq[0][1] = RD_A(bb, 2 * (qd), 1);  \
    aq[1][0] = RD_A(bb, 2 * (qd) + 1, 0); aq[1][1] = RD_A(bb, 2 * (qd) + 1, 1); \
} while (0)

#define MFMA1(mi, ni, ks) acc[mi][ni] = __builtin_amdgcn_mfma_f32_16x16x32_bf16( \
    aq[(mi) & 1][ks], bq[ni][ks], acc[mi][ni], 0, 0, 0)

#define MFMA_Q(qd) do {                                                                      \
    MFMA1(2*(qd),   0, 0); MFMA1(2*(qd),   1, 0); MFMA1(2*(qd),   2, 0); MFMA1(2*(qd),   3, 0); \
    MFMA1(2*(qd)+1, 0, 0); MFMA1(2*(qd)+1, 1, 0); MFMA1(2*(qd)+1, 2, 0); MFMA1(2*(qd)+1, 3, 0); \
    MFMA1(2*(qd),   0, 1); MFMA1(2*(qd),   1, 1); MFMA1(2*(qd),   2, 1); MFMA1(2*(qd),   3, 1); \
    MFMA1(2*(qd)+1, 0, 1); MFMA1(2*(qd)+1, 1, 1); MFMA1(2*(qd)+1, 2, 1); MFMA1(2*(qd)+1, 3, 1); \
} while (0)

#define BAR1_MFMA(qd) do {                                   \
    __builtin_amdgcn_s_barrier();                            \
    asm volatile("s_waitcnt lgkmcnt(0)" ::: "memory");       \
    __builtin_amdgcn_sched_barrier(0);                       \
    __builtin_amdgcn_s_setprio(1);                           \
    MFMA_Q(qd);                                              \
    __builtin_amdgcn_s_setprio(0);                           \
} while (0)
#define BAR2() __builtin_amdgcn_s_barrier()
#define VMW4() asm volatile("s_waitcnt vmcnt(4)" ::: "memory")
#define VMW0() asm volatile("s_waitcnt vmcnt(0)" ::: "memory")

__global__ __launch_bounds__(512, 2) void gemm_bt(const u16* __restrict__ A,
                                                  const u16* __restrict__ B,
                                                  __hip_bfloat16* __restrict__ C) {
    // 2 buffers x 256 rows x 64 cols bf16, A and B: 128 KiB total
    __shared__ __align__(16) u16 As[2 * 256 * 64];
    __shared__ __align__(16) u16 Bs[2 * 256 * 64];

    // T1: XCD-aware bijective swizzle (160 % 8 == 0); nt-major chunks share B panels per XCD
    int orig = blockIdx.x;
    int wgid = (orig & 7) * 20 + (orig >> 3);
    int mt = wgid % 10, nt = wgid / 10;
    int m0 = mt * 256, n0 = nt * 256;

    int t = threadIdx.x;
    int w = t >> 6, L = t & 63;          // wave 0..7, lane
    int wm = w >> 2, wn = w & 3;         // wave row/col: 2M x 4N, per-wave 128x64
    int q = L >> 4, lm = L & 15;         // MFMA lane decomposition
    int lr = L >> 3, ls = L & 7;         // staging lane decomposition

    // staging global base (per-lane pre-swizzled column)
    int csw = (ls ^ lr) * 8;
    const u16* gA0 = A + (size_t)(m0 + lr) * K_DIM + csw;
    const u16* gB0 = B + (size_t)(n0 + lr) * K_DIM + csw;
    int ldsw = w * 1024;                 // this wave's j=0 slice within a half (u16)

    // ds_read addressing: element (r,c) lives at r*64 + (c ^ ((r&7)<<3))
    int sw = (lm & 7) << 3;
    int arow = (wm * 128 + lm) * 64;
    int brow = (wn * 64 + lm) * 64;
    int col[2] = { (q * 8) ^ sw, (32 + q * 8) ^ sw };

    floatx4 acc[8][4];
    floatx4 z = {0.f, 0.f, 0.f, 0.f};
#pragma unroll
    for (int i = 0; i < 8; ++i)
#pragma unroll
        for (int j = 0; j < 4; ++j) acc[i][j] = z;

    short8 aq[2][2], bq[4][2];

    // ---- prologue: tile0 -> buf0 (A+B), tile1.B -> buf1; leave tile1.B in flight ----
    STG(gA0, As, 0, 0, 0); STG(gA0, As, 0, 1, 0);
    STG(gB0, Bs, 0, 0, 0); STG(gB0, Bs, 0, 1, 0);
    STG(gB0, Bs, 1, 0, 1); STG(gB0, Bs, 1, 1, 1);
    VMW4();                              // tile0 complete; tile1.B (4 loads) outstanding
    BAR2();

    // ---- main loop: iteration computes tiles T=2it (buf0), T+1 (buf1) ----
    for (int it = 0; it < 15; ++it) {
        int T = 2 * it;
        // Ph0: B(all)+A(q0) of buf0; stage (T+1).A -> buf1
        READ_BALL(0); READ_AQ(0, 0);
        STG(gA0, As, 1, 0, T + 1); STG(gA0, As, 1, 1, T + 1);
        BAR1_MFMA(0); BAR2();
        // Ph1: A(q1); stage (T+2).B-h0 -> buf0
        READ_AQ(0, 1);
        STG(gB0, Bs, 0, 0, T + 2);
        BAR1_MFMA(1); BAR2();
        // Ph2: A(q2); stage (T+2).B-h1 -> buf0
        READ_AQ(0, 2);
        STG(gB0, Bs, 0, 1, T + 2);
        BAR1_MFMA(2); BAR2();
        // Ph3: A(q3); counted wait completes (T+1).A/B before any wave enters Ph4
        READ_AQ(0, 3);
        BAR1_MFMA(3); VMW4(); BAR2();
        // Ph4: B(all)+A(q0) of buf1; stage (T+2).A -> buf0
        READ_BALL(1); READ_AQ(1, 0);
        STG(gA0, As, 0, 0, T + 2); STG(gA0, As, 0, 1, T + 2);
        BAR1_MFMA(0); BAR2();
        // Ph5: A(q1); stage (T+3).B-h0 -> buf1
        READ_AQ(1, 1);
        STG(gB0, Bs, 1, 0, T + 3);
        BAR1_MFMA(1); BAR2();
        // Ph6: A(q2); stage (T+3).B-h1 -> buf1
        READ_AQ(1, 2);
        STG(gB0, Bs, 1, 1, T + 3);
        BAR1_MFMA(2); BAR2();
        // Ph7: A(q3); counted wait completes (T+2) before next Ph0
        READ_AQ(1, 3);
        BAR1_MFMA(3); VMW4(); BAR2();
    }

    // ---- epilogue iteration: tiles 30 (buf0), 31 (buf1) ----
    READ_BALL(0); READ_AQ(0, 0);
    STG(gA0, As, 1, 0, 31); STG(gA0, As, 1, 1, 31);
    BAR1_MFMA(0); BAR2();
    READ_AQ(0, 1); BAR1_MFMA(1); BAR2();
    READ_AQ(0, 2); BAR1_MFMA(2); BAR2();
    READ_AQ(0, 3); BAR1_MFMA(3); VMW0(); BAR2();
    READ_BALL(1); READ_AQ(1, 0); BAR1_MFMA(0); BAR2();
    READ_AQ(1, 1); BAR1_MFMA(1); BAR2();
    READ_AQ(1, 2); BAR1_MFMA(2); BAR2();
    READ_AQ(1, 3); BAR1_MFMA(3); BAR2();

    // ---- C-write. C/D layout: col=lane&15, row=(lane>>4)*4+reg ----
    if (m0 + 255 < H_ROWS) {
#pragma unroll
        for (int mi = 0; mi < 8; ++mi) {
            int gm = m0 + wm * 128 + mi * 16 + q * 4;
#pragma unroll
            for (int ni = 0; ni < 4; ++ni) {
                int gn = n0 + wn * 64 + ni * 16 + lm;
#pragma unroll
                for (int r = 0; r < 4; ++r)
                    C[(size_t)(gm + r) * NPIX + gn] = __float2bfloat16(acc[mi][ni][r]);
            }
        }
    } else {
#pragma unroll
        for (int mi = 0; mi < 8; ++mi) {
            int gm = m0 + wm * 128 + mi * 16 + q * 4;
#pragma unroll
            for (int ni = 0; ni < 4; ++ni) {
                int gn = n0 + wn * 64 + ni * 16 + lm;
#pragma unroll
                for (int r = 0; r < 4; ++r) {
                    int row = gm + r;
                    if (row < H_ROWS)
                        C[(size_t)row * NPIX + gn] = __float2bfloat16(acc[mi][ni][r]);
                }
            }
        }
    }
}

// ---------------- sigma_raw (conv rows of H) + BN stats (R7-validated) ----------------
__global__ void sigma_stats(const __hip_bfloat16* __restrict__ Hm, float* __restrict__ sraw,
                            float* __restrict__ stats) {
    int b = blockIdx.x;           // (n*9 + l)*4 + quarter
    int qq = b & 3, nl = b >> 2;
    int n = nl / 9, l = nl - n * 9;
    int t = threadIdx.x;
    int pix = qq * 256 + t;
    int y = pix >> 5, x = pix & 31;
    float v = 0.f;
#pragma unroll
    for (int k = 0; k < 9; ++k) {
        int yy = y + k / 3 - 1, xx = x + (k % 3) - 1;
        if (yy >= 0 && yy < 32 && xx >= 0 && xx < 32)
            v += __bfloat162float(Hm[(size_t)(2304 + k * 9 + l) * NPIX + n * HW + yy * 32 + xx]);
    }
    sraw[(size_t)nl * HW + pix] = v;
    __shared__ float r1[256], r2[256];
    r1[t] = v; r2[t] = v * v;
    __syncthreads();
    for (int s = 128; s > 0; s >>= 1) {
        if (t < s) { r1[t] += r1[t + s]; r2[t] += r2[t + s]; }
        __syncthreads();
    }
    if (t == 0) { atomicAdd(&stats[l], r1[0]); atomicAdd(&stats[9 + l], r2[0]); }
}

// ---------------- tail v3: lane->consecutive pixel (coalesced H reads), 2 o per block, pixel-halves ----------------
// grid 1024: b = n*256 + ph*128 + og; channels o = 2*og,2*og+1; pixels ph*512 + i*256 + t (i=0,1)
__global__ void tail(const __hip_bfloat16* __restrict__ Hm, const float* __restrict__ sraw,
                     const float* __restrict__ stats, const float* __restrict__ gamma,
                     const float* __restrict__ beta, float* __restrict__ out) {
    int b = blockIdx.x;
    int n = b >> 8, rem = b & 255;
    int ph = rem >> 7, og = rem & 127;
    int t = threadIdx.x;
    float mean[9], istd[9], gg[9], bb[9];
#pragma unroll
    for (int l = 0; l < 9; ++l) {
        float m = stats[l] * (1.f / 4096.f);
        float var = stats[9 + l] * (1.f / 4096.f) - m * m;
        mean[l] = m; istd[l] = rsqrtf(var + BN_EPS);
        gg[l] = gamma[l]; bb[l] = beta[l];
    }
    const __hip_bfloat16* hb = Hm + (size_t)(og * 2) * NPIX + (size_t)n * HW;
    float* ob = out + ((size_t)n * 256 + og * 2) * HW;
#pragma unroll
    for (int i = 0; i < 2; ++i) {
        int pix = ph * 512 + i * 256 + t;
        int y = pix >> 5, x = pix & 31;
        float v[9];
        float mx = -1e30f;
#pragma unroll
        for (int l = 0; l < 9; ++l) {
            float tv = (sraw[(size_t)(n * 9 + l) * HW + pix] - mean[l]) * istd[l];
            tv = tv * gg[l] + bb[l];
            v[l] = tv; mx = fmaxf(mx, tv);
        }
        float ssum = 0.f;
#pragma unroll
        for (int l = 0; l < 9; ++l) { v[l] = __expf(v[l] - mx); ssum += v[l]; }
        float inv = 1.f / ssum;
        float acc0 = 0.f, acc1 = 0.f;
#pragma unroll
        for (int l = 0; l < 9; ++l) {
            int dy = l / 3 - 1, dx = l % 3 - 1;
            int yy = y + dy, xx = x + dx;
            if (yy >= 0 && yy < 32 && xx >= 0 && xx < 32) {
                float sv = v[l] * inv;
                size_t hidx = (size_t)(l * 256) * NPIX + (size_t)(pix + dy * 32 + dx);
                acc0 += sv * __bfloat162float(hb[hidx]);
                acc1 += sv * __bfloat162float(hb[hidx + NPIX]);
            }
        }
        ob[pix] = acc0;
        ob[HW + pix] = acc1;
    }
}

extern "C" void kernel_launch(void* const* d_in, const int* in_sizes, int n_in,
                              void* d_out, int out_size, void* d_ws, size_t ws_size,
                              hipStream_t stream) {
    const float* x     = (const float*)d_in[0];
    const float* cw    = (const float*)d_in[1];
    const float* gamma = (const float*)d_in[2];
    const float* beta  = (const float*)d_in[3];
    const float* wgt   = (const float*)d_in[4];

    char* ws = (char*)d_ws;
    u16*   Abuf = (u16*)(ws + OFF_A);
    u16*   XT   = (u16*)(ws + OFF_XT);
    u16*   Hm   = (u16*)(ws + OFF_H);
    float* sraw = (float*)(ws + OFF_SRAW);
    float* stats= (float*)(ws + OFF_STAT);

    build_all<<<2314, 256, 0, stream>>>(x, wgt, cw, XT, Abuf, stats);
    gemm_bt<<<160, 512, 0, stream>>>(Abuf, XT, (__hip_bfloat16*)Hm);
    sigma_stats<<<N_IMG * KK * 4, 256, 0, stream>>>((const __hip_bfloat16*)Hm, sraw, stats);
    tail<<<1024, 256, 0, stream>>>((const __hip_bfloat16*)Hm, sraw, stats, gamma, beta, (float*)d_out);
}

// Round 2
// 170.867 us; speedup vs baseline: 1.0169x; 1.0169x over previous
//
#include <hip/hip_runtime.h>
#include <hip/hip_bf16.h>
#include <stdint.h>

typedef unsigned short u16;
typedef __attribute__((ext_vector_type(8))) short short8;
typedef __attribute__((ext_vector_type(4))) float floatx4;

#define N_IMG 4
#define C_IN  2048
#define HW    1024
#define KK    9
#define O_OUT 256
#define NPIX  4096          // N_IMG*HW
#define M_PAD  2560         // 10*256 GEMM M-tiles (2304 proj + 81 conv + pad)
#define H_ROWS 2432         // H rows actually stored (proj 2304 + conv 81 + pad)
#define K_DIM  2048
#define BN_EPS 1e-5f

// workspace offsets (bytes), 256-aligned
#define OFF_A    0u                // A: 2560*2048*2 = 10485760
#define OFF_XT   10485760u         // XT: 4096*2048*2 = 16777216
#define OFF_H    27262976u         // H: 2432*4096*2 = 19922944
#define OFF_SRAW 47185920u         // sraw: 36864*4
#define OFF_STAT 47333376u

// fp32 -> bf16 bits, round-to-nearest-even
__device__ __forceinline__ u16 f2b(float f) {
    unsigned u = __float_as_uint(f);
    return (u16)((u + 0x7FFFu + ((u >> 16) & 1u)) >> 16);
}

__device__ __forceinline__ void load8f(const float* base, size_t eidx, u16* out) {
    const float* p = base + eidx;
    float4 a = ((const float4*)p)[0];
    float4 b = ((const float4*)p)[1];
    float f[8] = {a.x, a.y, a.z, a.w, b.x, b.y, b.z, b.w};
#pragma unroll
    for (int j = 0; j < 8; ++j) out[j] = f2b(f[j]);
}

// ---------------- merged staging kernel (R10-validated, unchanged) ----------------
__global__ void build_all(const float* __restrict__ x, const float* __restrict__ wgt,
                          const float* __restrict__ cw, u16* __restrict__ xt,
                          u16* __restrict__ A, float* __restrict__ stats) {
    __shared__ __align__(16) u16 lds[9 * 2056];
    int b = blockIdx.x, t = threadIdx.x;
    if (b < 2048) {
        int c0 = (b & 31) * 64, p0 = ((b >> 5) & 15) * 64, n = b >> 9;
        int rp = t >> 3;                // channel-pair 0..31
        int pv = (t & 7) * 8;           // pixel group
        u16 h0[8], h1[8];
        load8f(x, (size_t)(n * C_IN + c0 + 2 * rp) * HW + p0 + pv, h0);
        load8f(x, (size_t)(n * C_IN + c0 + 2 * rp + 1) * HW + p0 + pv, h1);
        unsigned* l32 = (unsigned*)lds;   // [64 pixels][stride 35 u32]
#pragma unroll
        for (int j = 0; j < 8; ++j)
            l32[(pv + j) * 35 + rp] = (unsigned)h0[j] | ((unsigned)h1[j] << 16);
        __syncthreads();
        int pr = t >> 3, cq = (t & 7) * 4;   // pixel, u32-quad (8 channels)
        unsigned o0[4], o1[4];
#pragma unroll
        for (int i = 0; i < 4; ++i) {
            o0[i] = l32[pr * 35 + cq + i];
            o1[i] = l32[(pr + 32) * 35 + cq + i];
        }
        *(uint4*)(xt + (size_t)(n * HW + p0 + pr) * K_DIM + c0 + cq * 2) = *(uint4*)o0;
        *(uint4*)(xt + (size_t)(n * HW + p0 + pr + 32) * K_DIM + c0 + cq * 2) = *(uint4*)o1;
    } else if (b < 2304) {
        int o = b - 2048;
        size_t base = (size_t)o * 18432;   // weight[o][c][l], e = c*9+l
        for (int i = 0; i < 9; ++i) {
            int e0 = (t + i * 256) * 8;
            u16 hv[8];
            load8f(wgt, base + e0, hv);
#pragma unroll
            for (int j = 0; j < 8; ++j) {
                int e = e0 + j;
                int c = e / 9, l = e - c * 9;
                lds[l * 2056 + c] = hv[j];
            }
        }
        __syncthreads();
        for (int l = 0; l < 9; ++l) {
            size_t row = (size_t)l * 256 + o;
            *(uint4*)(A + row * K_DIM + t * 8) = *(const uint4*)&lds[l * 2056 + t * 8];
        }
    } else if (b < 2313) {
        int l = b - 2304;
        size_t base = (size_t)l * 18432;    // conv_w[l][c][k], e = c*9+k
        for (int i = 0; i < 9; ++i) {
            int e0 = (t + i * 256) * 8;
            u16 hv[8];
            load8f(cw, base + e0, hv);
#pragma unroll
            for (int j = 0; j < 8; ++j) {
                int e = e0 + j;
                int c = e / 9, k = e - c * 9;
                lds[k * 2056 + c] = hv[j];
            }
        }
        __syncthreads();
        for (int k = 0; k < 9; ++k) {
            size_t row = 2304 + (size_t)k * 9 + l;
            *(uint4*)(A + row * K_DIM + t * 8) = *(const uint4*)&lds[k * 2056 + t * 8];
        }
    } else {
        // zero A rows 2385..2431 (rows 2432..2559 are garbage but each H row
        // depends only on its own A row; those H rows are never stored)
        uint4 z = {0, 0, 0, 0};
        uint4* dst = (uint4*)(A + (size_t)2385 * K_DIM);
        for (int i = t; i < (47 * 2048) / 8; i += 256) dst[i] = z;
        if (t < 18) stats[t] = 0.0f;
    }
}

// ---------------- GEMM: H = A * XT^T ----------------
// R12: 256x256 tile, BK=64, 8 waves (2Mx4N), 8-phase counted-vmcnt pipeline.
// vs R11: NO forced lgkmcnt(0) drain before MFMA clusters (compiler inserts
// incremental lgkmcnt waits; reads drain under MFMA), BAR2 of Ph1/2/5/6
// removed (hazard-free: B-restage only needs BAR2 of Ph0/Ph4; A overwrites
// only cross tile boundaries, guarded by VMW4+BAR2 at Ph3/Ph7), compiler
// fences around every barrier pin memory ops into their phase.
__device__ __forceinline__ void gload_lds16(const void* g, void* l) {
    __builtin_amdgcn_global_load_lds((__attribute__((address_space(1))) void*)(g),
                                     (__attribute__((address_space(3))) void*)(l), 16, 0, 0);
}

// stage one 128-row half-tile slice for this wave: 2 x global_load_lds (1 KB each)
// LDS dest is linear; global source column is pre-swizzled (rule #21):
// lane L covers row lr=L>>3 (within its 8-row slab), cols 8*((L&7)^lr)..+8
#define STG(gbase, ldsarr, bb, hh, kt) do {                                                        \
    gload_lds16((gbase) + (size_t)((hh) * 128 + (w * 2 + 0) * 8) * K_DIM + (size_t)(kt) * 64,      \
                (ldsarr) + (bb) * 16384 + (hh) * 8192 + ldsw);                                     \
    gload_lds16((gbase) + (size_t)((hh) * 128 + (w * 2 + 1) * 8) * K_DIM + (size_t)(kt) * 64,      \
                (ldsarr) + (bb) * 16384 + (hh) * 8192 + ldsw + 512);                               \
} while (0)

#define RD_A(bb, mi, ks) (*(const short8*)(As + (bb) * 16384 + arow + (mi) * 1024 + col[ks]))
#define RD_B(bb, ni, ks) (*(const short8*)(Bs + (bb) * 16384 + brow + (ni) * 1024 + col[ks]))

// issue order matches MFMA consume order (ks-outer)
#define READ_BALL(bb) do {                                                   \
    bq[0][0] = RD_B(bb, 0, 0); bq[1][0] = RD_B(bb, 1, 0);                    \
    bq[2][0] = RD_B(bb, 2, 0); bq[3][0] = RD_B(bb, 3, 0);                    \
    bq[0][1] = RD_B(bb, 0, 1); bq[1][1] = RD_B(bb, 1, 1);                    \
    bq[2][1] = RD_B(bb, 2, 1); bq[3][1] = RD_B(bb, 3, 1);                    \
} while (0)

#define READ_AQ(bb, qd) do {                                                 \
    aq[0][0] = RD_A(bb, 2 * (qd), 0);     aq[1][0] = RD_A(bb, 2 * (qd) + 1, 0); \
    aq[0][1] = RD_A(bb, 2 * (qd), 1);     aq[1][1] = RD_A(bb, 2 * (qd) + 1, 1); \
} while (0)

#define MFMA1(mi, ni, ks) acc[mi][ni] = __builtin_amdgcn_mfma_f32_16x16x32_bf16( \
    aq[(mi) & 1][ks], bq[ni][ks], acc[mi][ni], 0, 0, 0)

// ks-outer, ni-inner: consumes aq[.][0]+bq[.][0] first, then ks=1 set
#define MFMA_Q(qd) do {                                                                      \
    MFMA1(2*(qd),   0, 0); MFMA1(2*(qd)+1, 0, 0); MFMA1(2*(qd),   1, 0); MFMA1(2*(qd)+1, 1, 0); \
    MFMA1(2*(qd),   2, 0); MFMA1(2*(qd)+1, 2, 0); MFMA1(2*(qd),   3, 0); MFMA1(2*(qd)+1, 3, 0); \
    MFMA1(2*(qd),   0, 1); MFMA1(2*(qd)+1, 0, 1); MFMA1(2*(qd),   1, 1); MFMA1(2*(qd)+1, 1, 1); \
    MFMA1(2*(qd),   2, 1); MFMA1(2*(qd)+1, 2, 1); MFMA1(2*(qd),   3, 1); MFMA1(2*(qd)+1, 3, 1); \
} while (0)

#define FENCE() asm volatile("" ::: "memory")
#define BARRIER() do { FENCE(); __builtin_amdgcn_s_barrier(); FENCE(); } while (0)

#define BAR1_MFMA(qd) do {                                   \
    BARRIER();                                               \
    __builtin_amdgcn_s_setprio(1);                           \
    MFMA_Q(qd);                                              \
    __builtin_amdgcn_s_setprio(0);                           \
} while (0)
#define VMW4() asm volatile("s_waitcnt vmcnt(4)" ::: "memory")
#define VMW0() asm volatile("s_waitcnt vmcnt(0)" ::: "memory")

__global__ __launch_bounds__(512, 2) void gemm_bt(const u16* __restrict__ A,
                                                  const u16* __restrict__ B,
                                                  __hip_bfloat16* __restrict__ C) {
    // 2 buffers x 256 rows x 64 cols bf16, A and B: 128 KiB total
    __shared__ __align__(16) u16 As[2 * 256 * 64];
    __shared__ __align__(16) u16 Bs[2 * 256 * 64];

    // T1: XCD-aware bijective swizzle (160 % 8 == 0); nt-major chunks share B panels per XCD
    int orig = blockIdx.x;
    int wgid = (orig & 7) * 20 + (orig >> 3);
    int mt = wgid % 10, nt = wgid / 10;
    int m0 = mt * 256, n0 = nt * 256;

    int t = threadIdx.x;
    int w = t >> 6, L = t & 63;          // wave 0..7, lane
    int wm = w >> 2, wn = w & 3;         // wave row/col: 2M x 4N, per-wave 128x64
    int q = L >> 4, lm = L & 15;         // MFMA lane decomposition
    int lr = L >> 3, ls = L & 7;         // staging lane decomposition

    // staging global base (per-lane pre-swizzled column)
    int csw = (ls ^ lr) * 8;
    const u16* gA0 = A + (size_t)(m0 + lr) * K_DIM + csw;
    const u16* gB0 = B + (size_t)(n0 + lr) * K_DIM + csw;
    int ldsw = w * 1024;                 // this wave's j=0 slice within a half (u16)

    // ds_read addressing: element (r,c) lives at r*64 + (c ^ ((r&7)<<3))
    int sw = (lm & 7) << 3;
    int arow = (wm * 128 + lm) * 64;
    int brow = (wn * 64 + lm) * 64;
    int col[2] = { (q * 8) ^ sw, (32 + q * 8) ^ sw };

    floatx4 acc[8][4];
    floatx4 z = {0.f, 0.f, 0.f, 0.f};
#pragma unroll
    for (int i = 0; i < 8; ++i)
#pragma unroll
        for (int j = 0; j < 4; ++j) acc[i][j] = z;

    short8 aq[2][2], bq[4][2];

    // ---- prologue: tile0 -> buf0 (A+B), tile1.B -> buf1; leave tile1.B in flight ----
    STG(gA0, As, 0, 0, 0); STG(gA0, As, 0, 1, 0);
    STG(gB0, Bs, 0, 0, 0); STG(gB0, Bs, 0, 1, 0);
    STG(gB0, Bs, 1, 0, 1); STG(gB0, Bs, 1, 1, 1);
    VMW4();                              // tile0 complete; tile1.B (4 loads) outstanding
    BARRIER();

    // ---- main loop: iteration computes tiles T=2it (buf0), T+1 (buf1) ----
    for (int it = 0; it < 15; ++it) {
        int T = 2 * it;
        // Ph0: B(all)+A(q0) of buf0; stage (T+1).A -> buf1
        READ_AQ(0, 0); READ_BALL(0);
        STG(gA0, As, 1, 0, T + 1); STG(gA0, As, 1, 1, T + 1);
        BAR1_MFMA(0);
        BARRIER();   // all waves' B-reads of tile T done -> Bs[buf0] may be restaged
        // Ph1: A(q1); stage (T+2).B-h0 -> buf0
        READ_AQ(0, 1);
        STG(gB0, Bs, 0, 0, T + 2);
        BAR1_MFMA(1);
        // Ph2: A(q2); stage (T+2).B-h1 -> buf0
        READ_AQ(0, 2);
        STG(gB0, Bs, 0, 1, T + 2);
        BAR1_MFMA(2);
        // Ph3: A(q3); counted wait completes (T+1).A/B before any wave enters Ph4
        READ_AQ(0, 3);
        BAR1_MFMA(3); VMW4(); BARRIER();
        // Ph4: B(all)+A(q0) of buf1; stage (T+2).A -> buf0
        READ_AQ(1, 0); READ_BALL(1);
        STG(gA0, As, 0, 0, T + 2); STG(gA0, As, 0, 1, T + 2);
        BAR1_MFMA(0);
        BARRIER();   // all waves' B-reads of tile T+1 done -> Bs[buf1] may be restaged
        // Ph5: A(q1); stage (T+3).B-h0 -> buf1
        READ_AQ(1, 1);
        STG(gB0, Bs, 1, 0, T + 3);
        BAR1_MFMA(1);
        // Ph6: A(q2); stage (T+3).B-h1 -> buf1
        READ_AQ(1, 2);
        STG(gB0, Bs, 1, 1, T + 3);
        BAR1_MFMA(2);
        // Ph7: A(q3); counted wait completes (T+2) before next Ph0
        READ_AQ(1, 3);
        BAR1_MFMA(3); VMW4(); BARRIER();
    }

    // ---- epilogue iteration: tiles 30 (buf0), 31 (buf1) ----
    READ_AQ(0, 0); READ_BALL(0);
    STG(gA0, As, 1, 0, 31); STG(gA0, As, 1, 1, 31);
    BAR1_MFMA(0);
    READ_AQ(0, 1); BAR1_MFMA(1);
    READ_AQ(0, 2); BAR1_MFMA(2);
    READ_AQ(0, 3); BAR1_MFMA(3); VMW0(); BARRIER();
    READ_AQ(1, 0); READ_BALL(1); BAR1_MFMA(0);
    READ_AQ(1, 1); BAR1_MFMA(1);
    READ_AQ(1, 2); BAR1_MFMA(2);
    READ_AQ(1, 3); BAR1_MFMA(3);

    // ---- C-write. C/D layout: col=lane&15, row=(lane>>4)*4+reg ----
    if (m0 + 255 < H_ROWS) {
#pragma unroll
        for (int mi = 0; mi < 8; ++mi) {
            int gm = m0 + wm * 128 + mi * 16 + q * 4;
#pragma unroll
            for (int ni = 0; ni < 4; ++ni) {
                int gn = n0 + wn * 64 + ni * 16 + lm;
#pragma unroll
                for (int r = 0; r < 4; ++r)
                    C[(size_t)(gm + r) * NPIX + gn] = __float2bfloat16(acc[mi][ni][r]);
            }
        }
    } else {
#pragma unroll
        for (int mi = 0; mi < 8; ++mi) {
            int gm = m0 + wm * 128 + mi * 16 + q * 4;
#pragma unroll
            for (int ni = 0; ni < 4; ++ni) {
                int gn = n0 + wn * 64 + ni * 16 + lm;
#pragma unroll
                for (int r = 0; r < 4; ++r) {
                    int row = gm + r;
                    if (row < H_ROWS)
                        C[(size_t)row * NPIX + gn] = __float2bfloat16(acc[mi][ni][r]);
                }
            }
        }
    }
}

// ---------------- sigma_raw (conv rows of H) + BN stats (R7-validated) ----------------
__global__ void sigma_stats(const __hip_bfloat16* __restrict__ Hm, float* __restrict__ sraw,
                            float* __restrict__ stats) {
    int b = blockIdx.x;           // (n*9 + l)*4 + quarter
    int qq = b & 3, nl = b >> 2;
    int n = nl / 9, l = nl - n * 9;
    int t = threadIdx.x;
    int pix = qq * 256 + t;
    int y = pix >> 5, x = pix & 31;
    float v = 0.f;
#pragma unroll
    for (int k = 0; k < 9; ++k) {
        int yy = y + k / 3 - 1, xx = x + (k % 3) - 1;
        if (yy >= 0 && yy < 32 && xx >= 0 && xx < 32)
            v += __bfloat162float(Hm[(size_t)(2304 + k * 9 + l) * NPIX + n * HW + yy * 32 + xx]);
    }
    sraw[(size_t)nl * HW + pix] = v;
    __shared__ float r1[256], r2[256];
    r1[t] = v; r2[t] = v * v;
    __syncthreads();
    for (int s = 128; s > 0; s >>= 1) {
        if (t < s) { r1[t] += r1[t + s]; r2[t] += r2[t + s]; }
        __syncthreads();
    }
    if (t == 0) { atomicAdd(&stats[l], r1[0]); atomicAdd(&stats[9 + l], r2[0]); }
}

// ---------------- tail v3: lane->consecutive pixel (coalesced H reads), 2 o per block, pixel-halves ----------------
// grid 1024: b = n*256 + ph*128 + og; channels o = 2*og,2*og+1; pixels ph*512 + i*256 + t (i=0,1)
__global__ void tail(const __hip_bfloat16* __restrict__ Hm, const float* __restrict__ sraw,
                     const float* __restrict__ stats, const float* __restrict__ gamma,
                     const float* __restrict__ beta, float* __restrict__ out) {
    int b = blockIdx.x;
    int n = b >> 8, rem = b & 255;
    int ph = rem >> 7, og = rem & 127;
    int t = threadIdx.x;
    float mean[9], istd[9], gg[9], bb[9];
#pragma unroll
    for (int l = 0; l < 9; ++l) {
        float m = stats[l] * (1.f / 4096.f);
        float var = stats[9 + l] * (1.f / 4096.f) - m * m;
        mean[l] = m; istd[l] = rsqrtf(var + BN_EPS);
        gg[l] = gamma[l]; bb[l] = beta[l];
    }
    const __hip_bfloat16* hb = Hm + (size_t)(og * 2) * NPIX + (size_t)n * HW;
    float* ob = out + ((size_t)n * 256 + og * 2) * HW;
#pragma unroll
    for (int i = 0; i < 2; ++i) {
        int pix = ph * 512 + i * 256 + t;
        int y = pix >> 5, x = pix & 31;
        float v[9];
        float mx = -1e30f;
#pragma unroll
        for (int l = 0; l < 9; ++l) {
            float tv = (sraw[(size_t)(n * 9 + l) * HW + pix] - mean[l]) * istd[l];
            tv = tv * gg[l] + bb[l];
            v[l] = tv; mx = fmaxf(mx, tv);
        }
        float ssum = 0.f;
#pragma unroll
        for (int l = 0; l < 9; ++l) { v[l] = __expf(v[l] - mx); ssum += v[l]; }
        float inv = 1.f / ssum;
        float acc0 = 0.f, acc1 = 0.f;
#pragma unroll
        for (int l = 0; l < 9; ++l) {
            int dy = l / 3 - 1, dx = l % 3 - 1;
            int yy = y + dy, xx = x + dx;
            if (yy >= 0 && yy < 32 && xx >= 0 && xx < 32) {
                float sv = v[l] * inv;
                size_t hidx = (size_t)(l * 256) * NPIX + (size_t)(pix + dy * 32 + dx);
                acc0 += sv * __bfloat162float(hb[hidx]);
                acc1 += sv * __bfloat162float(hb[hidx + NPIX]);
            }
        }
        ob[pix] = acc0;
        ob[HW + pix] = acc1;
    }
}

extern "C" void kernel_launch(void* const* d_in, const int* in_sizes, int n_in,
                              void* d_out, int out_size, void* d_ws, size_t ws_size,
                              hipStream_t stream) {
    const float* x     = (const float*)d_in[0];
    const float* cw    = (const float*)d_in[1];
    const float* gamma = (const float*)d_in[2];
    const float* beta  = (const float*)d_in[3];
    const float* wgt   = (const float*)d_in[4];

    char* ws = (char*)d_ws;
    u16*   Abuf = (u16*)(ws + OFF_A);
    u16*   XT   = (u16*)(ws + OFF_XT);
    u16*   Hm   = (u16*)(ws + OFF_H);
    float* sraw = (float*)(ws + OFF_SRAW);
    float* stats= (float*)(ws + OFF_STAT);

    build_all<<<2314, 256, 0, stream>>>(x, wgt, cw, XT, Abuf, stats);
    gemm_bt<<<160, 512, 0, stream>>>(Abuf, XT, (__hip_bfloat16*)Hm);
    sigma_stats<<<N_IMG * KK * 4, 256, 0, stream>>>((const __hip_bfloat16*)Hm, sraw, stats);
    tail<<<1024, 256, 0, stream>>>((const __hip_bfloat16*)Hm, sraw, stats, gamma, beta, (float*)d_out);
}

// Round 3
// 159.780 us; speedup vs baseline: 1.0875x; 1.0694x over previous
//
#include <hip/hip_runtime.h>
#include <hip/hip_bf16.h>
#include <stdint.h>

typedef unsigned short u16;
typedef __attribute__((ext_vector_type(8))) short short8;
typedef __attribute__((ext_vector_type(4))) float floatx4;

#define N_IMG 4
#define C_IN  2048
#define HW    1024
#define KK    9
#define O_OUT 256
#define NPIX  4096          // N_IMG*HW
#define M_PAD  2560         // 16 M-tiles x 160 rows (2304 proj + 81 conv + pad)
#define H_ROWS 2432         // H rows actually stored (proj 2304 + conv 81 + pad)
#define K_DIM  2048
#define BN_EPS 1e-5f

// workspace offsets (bytes), 256-aligned
#define OFF_A    0u                // A: 2560*2048*2 = 10485760
#define OFF_XT   10485760u         // XT: 4096*2048*2 = 16777216
#define OFF_H    27262976u         // H: 2432*4096*2 = 19922944
#define OFF_SRAW 47185920u         // sraw: 36864*4
#define OFF_STAT 47333376u

// fp32 -> bf16 bits, round-to-nearest-even
__device__ __forceinline__ u16 f2b(float f) {
    unsigned u = __float_as_uint(f);
    return (u16)((u + 0x7FFFu + ((u >> 16) & 1u)) >> 16);
}

__device__ __forceinline__ void load8f(const float* base, size_t eidx, u16* out) {
    const float* p = base + eidx;
    float4 a = ((const float4*)p)[0];
    float4 b = ((const float4*)p)[1];
    float f[8] = {a.x, a.y, a.z, a.w, b.x, b.y, b.z, b.w};
#pragma unroll
    for (int j = 0; j < 8; ++j) out[j] = f2b(f[j]);
}

// ---------------- merged staging kernel (R10-validated, unchanged) ----------------
__global__ void build_all(const float* __restrict__ x, const float* __restrict__ wgt,
                          const float* __restrict__ cw, u16* __restrict__ xt,
                          u16* __restrict__ A, float* __restrict__ stats) {
    __shared__ __align__(16) u16 lds[9 * 2056];
    int b = blockIdx.x, t = threadIdx.x;
    if (b < 2048) {
        int c0 = (b & 31) * 64, p0 = ((b >> 5) & 15) * 64, n = b >> 9;
        int rp = t >> 3;                // channel-pair 0..31
        int pv = (t & 7) * 8;           // pixel group
        u16 h0[8], h1[8];
        load8f(x, (size_t)(n * C_IN + c0 + 2 * rp) * HW + p0 + pv, h0);
        load8f(x, (size_t)(n * C_IN + c0 + 2 * rp + 1) * HW + p0 + pv, h1);
        unsigned* l32 = (unsigned*)lds;   // [64 pixels][stride 35 u32]
#pragma unroll
        for (int j = 0; j < 8; ++j)
            l32[(pv + j) * 35 + rp] = (unsigned)h0[j] | ((unsigned)h1[j] << 16);
        __syncthreads();
        int pr = t >> 3, cq = (t & 7) * 4;   // pixel, u32-quad (8 channels)
        unsigned o0[4], o1[4];
#pragma unroll
        for (int i = 0; i < 4; ++i) {
            o0[i] = l32[pr * 35 + cq + i];
            o1[i] = l32[(pr + 32) * 35 + cq + i];
        }
        *(uint4*)(xt + (size_t)(n * HW + p0 + pr) * K_DIM + c0 + cq * 2) = *(uint4*)o0;
        *(uint4*)(xt + (size_t)(n * HW + p0 + pr + 32) * K_DIM + c0 + cq * 2) = *(uint4*)o1;
    } else if (b < 2304) {
        int o = b - 2048;
        size_t base = (size_t)o * 18432;   // weight[o][c][l], e = c*9+l
        for (int i = 0; i < 9; ++i) {
            int e0 = (t + i * 256) * 8;
            u16 hv[8];
            load8f(wgt, base + e0, hv);
#pragma unroll
            for (int j = 0; j < 8; ++j) {
                int e = e0 + j;
                int c = e / 9, l = e - c * 9;
                lds[l * 2056 + c] = hv[j];
            }
        }
        __syncthreads();
        for (int l = 0; l < 9; ++l) {
            size_t row = (size_t)l * 256 + o;
            *(uint4*)(A + row * K_DIM + t * 8) = *(const uint4*)&lds[l * 2056 + t * 8];
        }
    } else if (b < 2313) {
        int l = b - 2304;
        size_t base = (size_t)l * 18432;    // conv_w[l][c][k], e = c*9+k
        for (int i = 0; i < 9; ++i) {
            int e0 = (t + i * 256) * 8;
            u16 hv[8];
            load8f(cw, base + e0, hv);
#pragma unroll
            for (int j = 0; j < 8; ++j) {
                int e = e0 + j;
                int c = e / 9, k = e - c * 9;
                lds[k * 2056 + c] = hv[j];
            }
        }
        __syncthreads();
        for (int k = 0; k < 9; ++k) {
            size_t row = 2304 + (size_t)k * 9 + l;
            *(uint4*)(A + row * K_DIM + t * 8) = *(const uint4*)&lds[k * 2056 + t * 8];
        }
    } else {
        // zero A rows 2385..2431 (rows 2432..2559 are garbage; each H row
        // depends only on its own A row and rows >=2432 are never stored;
        // garbage/valid rows never share an MFMA fragment since 2432%16==0)
        uint4 z = {0, 0, 0, 0};
        uint4* dst = (uint4*)(A + (size_t)2385 * K_DIM);
        for (int i = t; i < (47 * 2048) / 8; i += 256) dst[i] = z;
        if (t < 18) stats[t] = 0.0f;
    }
}

// ---------------- GEMM: H = A * XT^T ----------------
// R13: 160x256 tile, BK=64, 8 waves (2Mx4N, per-wave 80x64), grid 16x16=256
// blocks -> every CU gets exactly one block (R12's 160-block grid left 96
// CUs idle). 6-phase iteration (2 K-tiles x 3 sub-phases: mi{0,1},{2,3},{4})
// with counted vmcnt: VMW4 = "keep 4 newest B-loads, drain older" -- valid
// for the uneven per-wave A-load count (waves 0-3 stage 3 quanta, 4-7 stage 2).
__device__ __forceinline__ void gload_lds16(const void* g, void* l) {
    __builtin_amdgcn_global_load_lds((__attribute__((address_space(1))) void*)(g),
                                     (__attribute__((address_space(3))) void*)(l), 16, 0, 0);
}

// A tile = 160 rows x 64 cols = 20 quanta (8 rows each); wave w stages quanta
// {w, w+8} and (w<4) w+16. LDS dest linear; global source col pre-swizzled.
#define STG_A(bb, kt) do {                                                                   \
    gload_lds16(gA0 + (size_t)(w * 8) * K_DIM + (size_t)(kt) * 64,                           \
                As + (bb) * 10240 + w * 512);                                                \
    gload_lds16(gA0 + (size_t)((w + 8) * 8) * K_DIM + (size_t)(kt) * 64,                     \
                As + (bb) * 10240 + (w + 8) * 512);                                          \
    if (w < 4)                                                                               \
        gload_lds16(gA0 + (size_t)((w + 16) * 8) * K_DIM + (size_t)(kt) * 64,                \
                    As + (bb) * 10240 + (w + 16) * 512);                                     \
} while (0)

// B half-tile hh (128 rows): wave w covers rows hh*128 + w*16 .. +15 via 2 loads
#define STG_B(bb, hh, kt) do {                                                               \
    gload_lds16(gB0 + (size_t)((hh) * 128 + (w * 2 + 0) * 8) * K_DIM + (size_t)(kt) * 64,    \
                Bs + (bb) * 16384 + (hh) * 8192 + w * 1024);                                 \
    gload_lds16(gB0 + (size_t)((hh) * 128 + (w * 2 + 1) * 8) * K_DIM + (size_t)(kt) * 64,    \
                Bs + (bb) * 16384 + (hh) * 8192 + w * 1024 + 512);                           \
} while (0)

#define RD_A(bb, mi, ks) (*(const short8*)(As + (bb) * 10240 + arow + (mi) * 1024 + col[ks]))
#define RD_B(bb, ni, ks) (*(const short8*)(Bs + (bb) * 16384 + brow + (ni) * 1024 + col[ks]))

// issue order matches MFMA consume order (ks-outer)
#define READ_BALL(bb) do {                                                   \
    bq[0][0] = RD_B(bb, 0, 0); bq[1][0] = RD_B(bb, 1, 0);                    \
    bq[2][0] = RD_B(bb, 2, 0); bq[3][0] = RD_B(bb, 3, 0);                    \
    bq[0][1] = RD_B(bb, 0, 1); bq[1][1] = RD_B(bb, 1, 1);                    \
    bq[2][1] = RD_B(bb, 2, 1); bq[3][1] = RD_B(bb, 3, 1);                    \
} while (0)

#define READ_A2(bb, mlo, mhi) do {                                           \
    aq[0][0] = RD_A(bb, mlo, 0); aq[1][0] = RD_A(bb, mhi, 0);                \
    aq[0][1] = RD_A(bb, mlo, 1); aq[1][1] = RD_A(bb, mhi, 1);                \
} while (0)

#define READ_A1(bb, m) do {                                                  \
    aq[0][0] = RD_A(bb, m, 0); aq[0][1] = RD_A(bb, m, 1);                    \
} while (0)

#define MF(a, b, c) __builtin_amdgcn_mfma_f32_16x16x32_bf16(a, b, c, 0, 0, 0)

#define MFMA_PAIR(mlo, mhi) do {                                                             \
    acc[mlo][0] = MF(aq[0][0], bq[0][0], acc[mlo][0]); acc[mhi][0] = MF(aq[1][0], bq[0][0], acc[mhi][0]); \
    acc[mlo][1] = MF(aq[0][0], bq[1][0], acc[mlo][1]); acc[mhi][1] = MF(aq[1][0], bq[1][0], acc[mhi][1]); \
    acc[mlo][2] = MF(aq[0][0], bq[2][0], acc[mlo][2]); acc[mhi][2] = MF(aq[1][0], bq[2][0], acc[mhi][2]); \
    acc[mlo][3] = MF(aq[0][0], bq[3][0], acc[mlo][3]); acc[mhi][3] = MF(aq[1][0], bq[3][0], acc[mhi][3]); \
    acc[mlo][0] = MF(aq[0][1], bq[0][1], acc[mlo][0]); acc[mhi][0] = MF(aq[1][1], bq[0][1], acc[mhi][0]); \
    acc[mlo][1] = MF(aq[0][1], bq[1][1], acc[mlo][1]); acc[mhi][1] = MF(aq[1][1], bq[1][1], acc[mhi][1]); \
    acc[mlo][2] = MF(aq[0][1], bq[2][1], acc[mlo][2]); acc[mhi][2] = MF(aq[1][1], bq[2][1], acc[mhi][2]); \
    acc[mlo][3] = MF(aq[0][1], bq[3][1], acc[mlo][3]); acc[mhi][3] = MF(aq[1][1], bq[3][1], acc[mhi][3]); \
} while (0)

#define MFMA_ONE(m) do {                                                                     \
    acc[m][0] = MF(aq[0][0], bq[0][0], acc[m][0]); acc[m][1] = MF(aq[0][0], bq[1][0], acc[m][1]); \
    acc[m][2] = MF(aq[0][0], bq[2][0], acc[m][2]); acc[m][3] = MF(aq[0][0], bq[3][0], acc[m][3]); \
    acc[m][0] = MF(aq[0][1], bq[0][1], acc[m][0]); acc[m][1] = MF(aq[0][1], bq[1][1], acc[m][1]); \
    acc[m][2] = MF(aq[0][1], bq[2][1], acc[m][2]); acc[m][3] = MF(aq[0][1], bq[3][1], acc[m][3]); \
} while (0)

#define FENCE() asm volatile("" ::: "memory")
#define BARRIER() do { FENCE(); __builtin_amdgcn_s_barrier(); FENCE(); } while (0)

#define BAR1_PAIR(mlo, mhi) do {                             \
    BARRIER();                                               \
    __builtin_amdgcn_s_setprio(1);                           \
    MFMA_PAIR(mlo, mhi);                                     \
    __builtin_amdgcn_s_setprio(0);                           \
} while (0)
#define BAR1_ONE(m) do {                                     \
    BARRIER();                                               \
    __builtin_amdgcn_s_setprio(1);                           \
    MFMA_ONE(m);                                             \
    __builtin_amdgcn_s_setprio(0);                           \
} while (0)
#define VMW4() asm volatile("s_waitcnt vmcnt(4)" ::: "memory")
#define VMW0() asm volatile("s_waitcnt vmcnt(0)" ::: "memory")

__global__ __launch_bounds__(512, 2) void gemm_bt(const u16* __restrict__ A,
                                                  const u16* __restrict__ B,
                                                  __hip_bfloat16* __restrict__ C) {
    // A: 2 x 160 x 64 bf16 = 40 KiB; B: 2 x 256 x 64 bf16 = 64 KiB
    __shared__ __align__(16) u16 As[2 * 160 * 64];
    __shared__ __align__(16) u16 Bs[2 * 256 * 64];

    // T1: XCD-aware bijective swizzle (256 % 8 == 0); each XCD: 2 nt-panels x 16 mt
    int orig = blockIdx.x;
    int wgid = (orig & 7) * 32 + (orig >> 3);
    int nt = wgid >> 4, mt = wgid & 15;
    int m0 = mt * 160, n0 = nt * 256;

    int t = threadIdx.x;
    int w = t >> 6, L = t & 63;          // wave 0..7, lane
    int wm = w >> 2, wn = w & 3;         // wave grid 2M x 4N, per-wave 80x64
    int q = L >> 4, lm = L & 15;         // MFMA lane decomposition
    int lr = L >> 3, ls = L & 7;         // staging lane decomposition

    // staging global base (per-lane pre-swizzled column)
    int csw = (ls ^ lr) * 8;
    const u16* gA0 = A + (size_t)(m0 + lr) * K_DIM + csw;
    const u16* gB0 = B + (size_t)(n0 + lr) * K_DIM + csw;

    // ds_read addressing: element (r,c) lives at r*64 + (c ^ ((r&7)<<3))
    int sw = (lm & 7) << 3;
    int arow = (wm * 80 + lm) * 64;      // 80 % 16 == 0 so (r&7) == (lm&7)
    int brow = (wn * 64 + lm) * 64;
    int col[2] = { (q * 8) ^ sw, (32 + q * 8) ^ sw };

    floatx4 acc[5][4];
    floatx4 z = {0.f, 0.f, 0.f, 0.f};
#pragma unroll
    for (int i = 0; i < 5; ++i)
#pragma unroll
        for (int j = 0; j < 4; ++j) acc[i][j] = z;

    short8 aq[2][2], bq[4][2];

    // ---- prologue: tile0 A+B -> buf0, tile1.B -> buf1 (left in flight) ----
    STG_A(0, 0);
    STG_B(0, 0, 0); STG_B(0, 1, 0);
    STG_B(1, 0, 1); STG_B(1, 1, 1);
    VMW4();                              // keep tile1.B (4 newest), drain tile0
    BARRIER();

    // ---- main loop: iteration computes tiles T=2it (buf0), T+1 (buf1) ----
    for (int it = 0; it < 15; ++it) {
        int T = 2 * it;
        // Ph0 (buf0): B(all)+A(mi0,1); stage (T+1).A -> buf1
        READ_A2(0, 0, 1); READ_BALL(0);
        STG_A(1, T + 1);
        BAR1_PAIR(0, 1);
        BARRIER();   // all waves' buf0-B reads issued -> Bs[buf0] may be restaged
        // Ph1: A(mi2,3); stage (T+2).B-h0 -> buf0
        READ_A2(0, 2, 3);
        STG_B(0, 0, T + 2);
        BAR1_PAIR(2, 3);
        // Ph2: A(mi4); stage (T+2).B-h1 -> buf0; tile switch
        READ_A1(0, 4);
        STG_B(0, 1, T + 2);
        BAR1_ONE(4);
        VMW4(); BARRIER();   // (T+1).A/B landed; keep (T+2).B in flight
        // Ph3 (buf1): B(all)+A(mi0,1); stage (T+2).A -> buf0
        READ_A2(1, 0, 1); READ_BALL(1);
        STG_A(0, T + 2);
        BAR1_PAIR(0, 1);
        BARRIER();   // Bs[buf1] may be restaged
        // Ph4: A(mi2,3); stage (T+3).B-h0 -> buf1
        READ_A2(1, 2, 3);
        STG_B(1, 0, T + 3);
        BAR1_PAIR(2, 3);
        // Ph5: A(mi4); stage (T+3).B-h1 -> buf1; tile switch
        READ_A1(1, 4);
        STG_B(1, 1, T + 3);
        BAR1_ONE(4);
        VMW4(); BARRIER();   // (T+2).A/B landed; keep (T+3).B in flight
    }

    // ---- epilogue: tiles 30 (buf0), 31 (buf1) ----
    READ_A2(0, 0, 1); READ_BALL(0);
    STG_A(1, 31);
    BAR1_PAIR(0, 1);
    READ_A2(0, 2, 3); BAR1_PAIR(2, 3);
    READ_A1(0, 4);    BAR1_ONE(4);
    VMW0(); BARRIER();                   // (31).A/B all landed
    READ_A2(1, 0, 1); READ_BALL(1); BAR1_PAIR(0, 1);
    READ_A2(1, 2, 3); BAR1_PAIR(2, 3);
    READ_A1(1, 4);    BAR1_ONE(4);

    // ---- C-write. C/D layout: col=lane&15, row=(lane>>4)*4+reg ----
    if (m0 + 159 < H_ROWS) {
#pragma unroll
        for (int mi = 0; mi < 5; ++mi) {
            int gm = m0 + wm * 80 + mi * 16 + q * 4;
#pragma unroll
            for (int ni = 0; ni < 4; ++ni) {
                int gn = n0 + wn * 64 + ni * 16 + lm;
#pragma unroll
                for (int r = 0; r < 4; ++r)
                    C[(size_t)(gm + r) * NPIX + gn] = __float2bfloat16(acc[mi][ni][r]);
            }
        }
    } else {
#pragma unroll
        for (int mi = 0; mi < 5; ++mi) {
            int gm = m0 + wm * 80 + mi * 16 + q * 4;
#pragma unroll
            for (int ni = 0; ni < 4; ++ni) {
                int gn = n0 + wn * 64 + ni * 16 + lm;
#pragma unroll
                for (int r = 0; r < 4; ++r) {
                    int row = gm + r;
                    if (row < H_ROWS)
                        C[(size_t)row * NPIX + gn] = __float2bfloat16(acc[mi][ni][r]);
                }
            }
        }
    }
}

// ---------------- sigma_raw (conv rows of H) + BN stats (R7-validated) ----------------
__global__ void sigma_stats(const __hip_bfloat16* __restrict__ Hm, float* __restrict__ sraw,
                            float* __restrict__ stats) {
    int b = blockIdx.x;           // (n*9 + l)*4 + quarter
    int qq = b & 3, nl = b >> 2;
    int n = nl / 9, l = nl - n * 9;
    int t = threadIdx.x;
    int pix = qq * 256 + t;
    int y = pix >> 5, x = pix & 31;
    float v = 0.f;
#pragma unroll
    for (int k = 0; k < 9; ++k) {
        int yy = y + k / 3 - 1, xx = x + (k % 3) - 1;
        if (yy >= 0 && yy < 32 && xx >= 0 && xx < 32)
            v += __bfloat162float(Hm[(size_t)(2304 + k * 9 + l) * NPIX + n * HW + yy * 32 + xx]);
    }
    sraw[(size_t)nl * HW + pix] = v;
    __shared__ float r1[256], r2[256];
    r1[t] = v; r2[t] = v * v;
    __syncthreads();
    for (int s = 128; s > 0; s >>= 1) {
        if (t < s) { r1[t] += r1[t + s]; r2[t] += r2[t + s]; }
        __syncthreads();
    }
    if (t == 0) { atomicAdd(&stats[l], r1[0]); atomicAdd(&stats[9 + l], r2[0]); }
}

// ---------------- tail v3: lane->consecutive pixel (coalesced H reads), 2 o per block, pixel-halves ----------------
// grid 1024: b = n*256 + ph*128 + og; channels o = 2*og,2*og+1; pixels ph*512 + i*256 + t (i=0,1)
__global__ void tail(const __hip_bfloat16* __restrict__ Hm, const float* __restrict__ sraw,
                     const float* __restrict__ stats, const float* __restrict__ gamma,
                     const float* __restrict__ beta, float* __restrict__ out) {
    int b = blockIdx.x;
    int n = b >> 8, rem = b & 255;
    int ph = rem >> 7, og = rem & 127;
    int t = threadIdx.x;
    float mean[9], istd[9], gg[9], bb[9];
#pragma unroll
    for (int l = 0; l < 9; ++l) {
        float m = stats[l] * (1.f / 4096.f);
        float var = stats[9 + l] * (1.f / 4096.f) - m * m;
        mean[l] = m; istd[l] = rsqrtf(var + BN_EPS);
        gg[l] = gamma[l]; bb[l] = beta[l];
    }
    const __hip_bfloat16* hb = Hm + (size_t)(og * 2) * NPIX + (size_t)n * HW;
    float* ob = out + ((size_t)n * 256 + og * 2) * HW;
#pragma unroll
    for (int i = 0; i < 2; ++i) {
        int pix = ph * 512 + i * 256 + t;
        int y = pix >> 5, x = pix & 31;
        float v[9];
        float mx = -1e30f;
#pragma unroll
        for (int l = 0; l < 9; ++l) {
            float tv = (sraw[(size_t)(n * 9 + l) * HW + pix] - mean[l]) * istd[l];
            tv = tv * gg[l] + bb[l];
            v[l] = tv; mx = fmaxf(mx, tv);
        }
        float ssum = 0.f;
#pragma unroll
        for (int l = 0; l < 9; ++l) { v[l] = __expf(v[l] - mx); ssum += v[l]; }
        float inv = 1.f / ssum;
        float acc0 = 0.f, acc1 = 0.f;
#pragma unroll
        for (int l = 0; l < 9; ++l) {
            int dy = l / 3 - 1, dx = l % 3 - 1;
            int yy = y + dy, xx = x + dx;
            if (yy >= 0 && yy < 32 && xx >= 0 && xx < 32) {
                float sv = v[l] * inv;
                size_t hidx = (size_t)(l * 256) * NPIX + (size_t)(pix + dy * 32 + dx);
                acc0 += sv * __bfloat162float(hb[hidx]);
                acc1 += sv * __bfloat162float(hb[hidx + NPIX]);
            }
        }
        ob[pix] = acc0;
        ob[HW + pix] = acc1;
    }
}

extern "C" void kernel_launch(void* const* d_in, const int* in_sizes, int n_in,
                              void* d_out, int out_size, void* d_ws, size_t ws_size,
                              hipStream_t stream) {
    const float* x     = (const float*)d_in[0];
    const float* cw    = (const float*)d_in[1];
    const float* gamma = (const float*)d_in[2];
    const float* beta  = (const float*)d_in[3];
    const float* wgt   = (const float*)d_in[4];

    char* ws = (char*)d_ws;
    u16*   Abuf = (u16*)(ws + OFF_A);
    u16*   XT   = (u16*)(ws + OFF_XT);
    u16*   Hm   = (u16*)(ws + OFF_H);
    float* sraw = (float*)(ws + OFF_SRAW);
    float* stats= (float*)(ws + OFF_STAT);

    build_all<<<2314, 256, 0, stream>>>(x, wgt, cw, XT, Abuf, stats);
    gemm_bt<<<256, 512, 0, stream>>>(Abuf, XT, (__hip_bfloat16*)Hm);
    sigma_stats<<<N_IMG * KK * 4, 256, 0, stream>>>((const __hip_bfloat16*)Hm, sraw, stats);
    tail<<<1024, 256, 0, stream>>>((const __hip_bfloat16*)Hm, sraw, stats, gamma, beta, (float*)d_out);
}